// Round 2
// baseline (471.526 us; speedup 1.0000x reference)
//
#include <hip/hip_runtime.h>

#define BT 10
#define CC 384
#define DH 64
#define CTXC 128
#define NS 4
#define SCALE_F 0.125f

// vout offsets (floats) per stage, aout base
#define VOFF0 0
#define VOFF1 24576000
#define VOFF2 30720000
#define VOFF3 32256000
#define AOUT_OFF 32640000

struct Params {
  const float* fmap0; const float* fmap1; const float* fmap2; const float* fmap3;
  const float* pos0;  const float* pos1;  const float* pos2;  const float* pos3;
  const float* audio0;const float* audio1;const float* audio2;const float* audio3;
  const float* ctx_proj_w; const float* ctx_proj_b; const float* pos_emb;
  const float* qk_w; const float* ctx_qk_w; const float* v_w; const float* ctx_v_w;
  const float* out_w; const float* out_b; const float* ctx_out_w; const float* ctx_out_b;
  float* out;
  float* r;        // ws (4,10,384)
  float* outvec;   // ws (4,10,384)
  float* xw;       // ws (4,10,384)
  float* simbuf;   // ws 85000 (atomically accumulated)
};

__device__ __forceinline__ int hw_of(int s){ return s==0?6400: s==1?1600: s==2?400:100; }
__device__ __forceinline__ int simoff(int s){ return s==0?0: s==1?64000: s==2?80000:84000; }
__device__ __forceinline__ const float* fm_of(const Params& P, int s){ return s==0?P.fmap0: s==1?P.fmap1: s==2?P.fmap2:P.fmap3; }
__device__ __forceinline__ const float* po_of(const Params& P, int s){ return s==0?P.pos0: s==1?P.pos1: s==2?P.pos2:P.pos3; }
__device__ __forceinline__ const float* au_of(const Params& P, int s){ return s==0?P.audio0: s==1?P.audio1: s==2?P.audio2:P.audio3; }

// ---------------- A: per-(s,b) small GEMVs: a, cqk, cv, r(=Wqk^T cqk * SCALE), outvec ----------------
__global__ __launch_bounds__(384) void k_pre(Params P) {
  const int s = blockIdx.x / BT, b = blockIdx.x % BT;
  const int tid = threadIdx.x;
  __shared__ float aud[CTXC], ctxv[CC], ctxpe[CC], cqk[DH], cvv[DH];
  const float* audio = au_of(P, s);
  if (tid < CTXC) aud[tid] = audio[b*CTXC + tid];
  __syncthreads();
  {
    float acc = P.ctx_proj_b[s*CC + tid];
    const float* wrow = P.ctx_proj_w + (size_t)(s*CC + tid)*CTXC;
    #pragma unroll 8
    for (int k = 0; k < CTXC; ++k) acc += wrow[k]*aud[k];
    ctxv[tid] = acc;
    ctxpe[tid] = acc + P.pos_emb[(s*5 + (b%5))*CC + tid];
  }
  __syncthreads();
  if (tid < DH) {
    float q = 0.f, v = 0.f;
    const float* wq = P.ctx_qk_w + (size_t)(s*DH + tid)*CC;
    const float* wv = P.ctx_v_w  + (size_t)(s*DH + tid)*CC;
    #pragma unroll 4
    for (int c = 0; c < CC; ++c) { q += wq[c]*ctxpe[c]; v += wv[c]*ctxv[c]; }
    cqk[tid] = q; cvv[tid] = v;
  }
  __syncthreads();
  {
    float rr = 0.f, ov = P.out_b[s*CC + tid];
    const float* wqk = P.qk_w + (size_t)s*DH*CC + tid;        // [d][tid], stride CC
    const float* wo  = P.out_w + (size_t)(s*CC + tid)*DH;
    #pragma unroll 4
    for (int d = 0; d < DH; ++d) { rr += wqk[(size_t)d*CC]*cqk[d]; ov += wo[d]*cvv[d]; }
    P.r[(s*BT+b)*CC + tid] = rr * SCALE_F;
    P.outvec[(s*BT+b)*CC + tid] = ov;
  }
}

// ---------------- B: sim[b,i] += sum_{c in part} (x+pos)[b,c,i] * r[b,c]  (8-way c split, float4) ----------------
__global__ __launch_bounds__(256) void k_sim(Params P) {
  const int bid = blockIdx.x;
  int s, b, chunk, part, HW;
  if (bid < 560)      { s=0; int l=bid;     b=l/56; int r2=l%56; chunk=r2>>3; part=r2&7; HW=6400; }
  else if (bid < 720) { s=1; int l=bid-560; b=l/16; int r2=l%16; chunk=r2>>3; part=r2&7; HW=1600; }
  else if (bid < 800) { s=2; int l=bid-720; b=l>>3; part=l&7; chunk=0; HW=400; }
  else                { s=3; int l=bid-800; b=l>>3; part=l&7; chunk=0; HW=100; }
  const int tid = threadIdx.x;
  const int c0 = part*48;
  const int hw4 = HW >> 2;

  __shared__ float rs[48];
  if (tid < 48) rs[tid] = P.r[(s*BT+b)*CC + c0 + tid];
  __syncthreads();

  const int i4 = chunk*256 + tid;
  if (i4 < hw4) {
    const float4* xp = (const float4*)(fm_of(P, s) + ((size_t)b*CC + c0)*HW) + i4;
    const float4* pp = (const float4*)(po_of(P, s) + ((size_t)b*CC + c0)*HW) + i4;
    float4 acc = {0.f, 0.f, 0.f, 0.f};
    #pragma unroll 8
    for (int c = 0; c < 48; ++c) {
      const float4 x = xp[(size_t)c*hw4];
      const float4 p = pp[(size_t)c*hw4];
      const float rc = rs[c];
      acc.x += (x.x + p.x) * rc;
      acc.y += (x.y + p.y) * rc;
      acc.z += (x.z + p.z) * rc;
      acc.w += (x.w + p.w) * rc;
    }
    float* dst = P.simbuf + simoff(s) + b*HW + i4*4;
    atomicAdd(dst + 0, acc.x);
    atomicAdd(dst + 1, acc.y);
    atomicAdd(dst + 2, acc.z);
    atomicAdd(dst + 3, acc.w);
  }
}

// ---------------- C1: softmax in place over i, per (s,b) ----------------
__global__ __launch_bounds__(256) void k_softmax(Params P) {
  const int s = blockIdx.x / BT, b = blockIdx.x % BT;
  const int HW = hw_of(s);
  float* sim = P.simbuf + simoff(s) + b*HW;
  const int tid = threadIdx.x;
  const int wid = tid >> 6, lane = tid & 63;
  __shared__ float red[4], red2[4];

  float m = -1e30f;
  for (int i = tid; i < HW; i += 256) m = fmaxf(m, sim[i]);
  #pragma unroll
  for (int off = 32; off; off >>= 1) m = fmaxf(m, __shfl_down(m, off));
  if (lane == 0) red[wid] = m;
  __syncthreads();
  if (tid == 0) { float mm = red[0]; for (int w2 = 1; w2 < 4; ++w2) mm = fmaxf(mm, red[w2]); red[0] = mm; }
  __syncthreads();
  m = red[0];

  float sum = 0.f;
  for (int i = tid; i < HW; i += 256) { float e = expf(sim[i] - m); sim[i] = e; sum += e; }
  #pragma unroll
  for (int off = 32; off; off >>= 1) sum += __shfl_down(sum, off);
  if (lane == 0) red2[wid] = sum;
  __syncthreads();
  if (tid == 0) { float ss = red2[0]; for (int w2 = 1; w2 < 4; ++w2) ss += red2[w2]; red2[0] = ss; }
  __syncthreads();
  const float invS = 1.f / red2[0];

  for (int i = tid; i < HW; i += 256) sim[i] *= invS;
}

// ---------------- C2: xw[s,b,c] = sum_i w[b,i] * x[b,c,i]  (one wave per c) ----------------
__global__ __launch_bounds__(256) void k_xw(Params P) {
  const int bid = blockIdx.x;
  const int sb = bid / 96, ct = bid % 96;
  const int s = sb / BT, b = sb % BT;
  const int HW = hw_of(s);
  const int wid = threadIdx.x >> 6, lane = threadIdx.x & 63;
  const int c = ct*4 + wid;
  const float* xrow = fm_of(P, s) + ((size_t)(b*CC + c))*HW;
  const float* wrow = P.simbuf + simoff(s) + b*HW;
  float ax=0.f, ay=0.f, az=0.f, aw=0.f;
  #pragma unroll 4
  for (int i0 = lane*4; i0 < HW; i0 += 256) {
    const float4 x4 = *(const float4*)(xrow + i0);
    const float4 w4 = *(const float4*)(wrow + i0);
    ax += x4.x*w4.x; ay += x4.y*w4.y; az += x4.z*w4.z; aw += x4.w*w4.w;
  }
  float acc = (ax + ay) + (az + aw);
  #pragma unroll
  for (int off = 32; off; off >>= 1) acc += __shfl_down(acc, off);
  if (lane == 0) P.xw[(s*BT+b)*CC + c] = acc;
}

// ---------------- D: ctxo = Wv @ xw; aout = Wco @ ctxo + bco ----------------
__global__ __launch_bounds__(384) void k_post(Params P) {
  const int s = blockIdx.x / BT, b = blockIdx.x % BT;
  const int tid = threadIdx.x;
  __shared__ float xws[CC], ctxo[DH];
  xws[tid] = P.xw[(s*BT+b)*CC + tid];
  __syncthreads();
  if (tid < DH) {
    float acc = 0.f;
    const float* wv = P.v_w + (size_t)(s*DH + tid)*CC;
    #pragma unroll 4
    for (int c = 0; c < CC; ++c) acc += wv[c]*xws[c];
    ctxo[tid] = acc;
  }
  __syncthreads();
  float ao = P.ctx_out_b[s*CC + tid];
  const float* wco = P.ctx_out_w + (size_t)(s*CC + tid)*DH;
  #pragma unroll 4
  for (int d = 0; d < DH; ++d) ao += wco[d]*ctxo[d];
  P.out[(size_t)AOUT_OFF + (s*BT+b)*CC + tid] = ao;
}

// ---------------- E: broadcast-fill vout, flat float4 stream, compile-time row length per branch ----------------
template<int F4PR, int VOFF, int OVOFF>
__device__ __forceinline__ void fill_one(const Params& P, int idx) {
  const int row = idx / F4PR;                 // magic-mul (compile-time divisor)
  const float val = P.outvec[OVOFF + row];
  const float4 v4 = {val, val, val, val};
  ((float4*)(P.out + VOFF))[idx] = v4;
}

__global__ __launch_bounds__(256) void k_fill(Params P) {
  const int gid = blockIdx.x * 256 + threadIdx.x;
  if (blockIdx.x < 24000)      fill_one<1600, VOFF0, 0>    (P, gid);
  else if (blockIdx.x < 30000) fill_one< 400, VOFF1, 3840> (P, gid - 24000*256);
  else if (blockIdx.x < 31500) fill_one< 100, VOFF2, 7680> (P, gid - 30000*256);
  else                         fill_one<  25, VOFF3, 11520>(P, gid - 31500*256);
}

extern "C" void kernel_launch(void* const* d_in, const int* in_sizes, int n_in,
                              void* d_out, int out_size, void* d_ws, size_t ws_size,
                              hipStream_t stream) {
  Params P;
  P.fmap0 = (const float*)d_in[0];  P.pos0 = (const float*)d_in[1];  P.audio0 = (const float*)d_in[2];
  P.fmap1 = (const float*)d_in[3];  P.pos1 = (const float*)d_in[4];  P.audio1 = (const float*)d_in[5];
  P.fmap2 = (const float*)d_in[6];  P.pos2 = (const float*)d_in[7];  P.audio2 = (const float*)d_in[8];
  P.fmap3 = (const float*)d_in[9];  P.pos3 = (const float*)d_in[10]; P.audio3 = (const float*)d_in[11];
  P.ctx_proj_w = (const float*)d_in[12]; P.ctx_proj_b = (const float*)d_in[13];
  P.pos_emb = (const float*)d_in[14];
  P.qk_w = (const float*)d_in[15];  P.ctx_qk_w = (const float*)d_in[16];
  P.v_w = (const float*)d_in[17];   P.ctx_v_w = (const float*)d_in[18];
  P.out_w = (const float*)d_in[19]; P.out_b = (const float*)d_in[20];
  P.ctx_out_w = (const float*)d_in[21]; P.ctx_out_b = (const float*)d_in[22];
  P.out = (float*)d_out;

  float* ws = (float*)d_ws;
  P.r      = ws;                 // 15360
  P.outvec = ws + 15360;         // 15360
  P.xw     = ws + 30720;         // 15360
  P.simbuf = ws + 46080;         // 85000

  hipMemsetAsync(P.simbuf, 0, 85000*sizeof(float), stream);
  k_pre    <<<NS*BT, 384, 0, stream>>>(P);
  k_sim    <<<880,   256, 0, stream>>>(P);
  k_softmax<<<NS*BT, 256, 0, stream>>>(P);
  k_xw     <<<3840,  256, 0, stream>>>(P);   // right after softmax: fmap may still be LLC-resident
  k_post   <<<NS*BT, 384, 0, stream>>>(P);
  k_fill   <<<31875, 256, 0, stream>>>(P);
}

// Round 3
// 441.049 us; speedup vs baseline: 1.0691x; 1.0691x over previous
//
#include <hip/hip_runtime.h>

#define BT 10
#define CC 384
#define DH 64
#define CTXC 128
#define NS 4
#define SCALE_F 0.125f

// vout offsets (floats) per stage, aout base
#define VOFF0 0
#define VOFF1 24576000
#define VOFF2 30720000
#define VOFF3 32256000
#define AOUT_OFF 32640000

struct Params {
  const float* fmap0; const float* fmap1; const float* fmap2; const float* fmap3;
  const float* pos0;  const float* pos1;  const float* pos2;  const float* pos3;
  const float* audio0;const float* audio1;const float* audio2;const float* audio3;
  const float* ctx_proj_w; const float* ctx_proj_b; const float* pos_emb;
  const float* qk_w; const float* ctx_qk_w; const float* v_w; const float* ctx_v_w;
  const float* out_w; const float* out_b; const float* ctx_out_w; const float* ctx_out_b;
  float* out;
  float* r;        // ws (4,10,384)
  float* outvec;   // ws (4,10,384)
  float* xw;       // ws (4,10,384)
  float* simbuf;   // ws 85000 (atomically accumulated)
};

__device__ __forceinline__ int hw_of(int s){ return s==0?6400: s==1?1600: s==2?400:100; }
__device__ __forceinline__ int simoff(int s){ return s==0?0: s==1?64000: s==2?80000:84000; }
__device__ __forceinline__ const float* fm_of(const Params& P, int s){ return s==0?P.fmap0: s==1?P.fmap1: s==2?P.fmap2:P.fmap3; }
__device__ __forceinline__ const float* po_of(const Params& P, int s){ return s==0?P.pos0: s==1?P.pos1: s==2?P.pos2:P.pos3; }
__device__ __forceinline__ const float* au_of(const Params& P, int s){ return s==0?P.audio0: s==1?P.audio1: s==2?P.audio2:P.audio3; }

// ---------------- A: per-(s,b) small GEMVs ----------------
__global__ __launch_bounds__(384) void k_pre(Params P) {
  const int s = blockIdx.x / BT, b = blockIdx.x % BT;
  const int tid = threadIdx.x;
  __shared__ float aud[CTXC], ctxv[CC], ctxpe[CC], cqk[DH], cvv[DH];
  __shared__ float pq[6][DH], pvv[6][DH];
  const float* audio = au_of(P, s);
  if (tid < CTXC) aud[tid] = audio[b*CTXC + tid];
  __syncthreads();
  {
    float acc = P.ctx_proj_b[s*CC + tid];
    const float* wrow = P.ctx_proj_w + (size_t)(s*CC + tid)*CTXC;
    #pragma unroll 16
    for (int k = 0; k < CTXC; ++k) acc += wrow[k]*aud[k];
    ctxv[tid] = acc;
    ctxpe[tid] = acc + P.pos_emb[(s*5 + (b%5))*CC + tid];
  }
  __syncthreads();
  // cqk/cvv: 64 outputs x 384 dot, split over 6 groups of 64 threads
  {
    const int g = tid >> 6, oid = tid & 63;
    float q = 0.f, v = 0.f;
    const float* wq = P.ctx_qk_w + (size_t)(s*DH + oid)*CC + g*64;
    const float* wv = P.ctx_v_w  + (size_t)(s*DH + oid)*CC + g*64;
    #pragma unroll 8
    for (int c = 0; c < 64; ++c) { q += wq[c]*ctxpe[g*64+c]; v += wv[c]*ctxv[g*64+c]; }
    pq[g][oid] = q; pvv[g][oid] = v;
  }
  __syncthreads();
  if (tid < DH) {
    float q = 0.f, v = 0.f;
    #pragma unroll
    for (int g2 = 0; g2 < 6; ++g2) { q += pq[g2][tid]; v += pvv[g2][tid]; }
    cqk[tid] = q; cvv[tid] = v;
  }
  __syncthreads();
  {
    float rr = 0.f, ov = P.out_b[s*CC + tid];
    const float* wqk = P.qk_w + (size_t)s*DH*CC + tid;        // [d][tid], stride CC
    const float* wo  = P.out_w + (size_t)(s*CC + tid)*DH;
    #pragma unroll 8
    for (int d = 0; d < DH; ++d) { rr += wqk[(size_t)d*CC]*cqk[d]; ov += wo[d]*cvv[d]; }
    P.r[(s*BT+b)*CC + tid] = rr * SCALE_F;
    P.outvec[(s*BT+b)*CC + tid] = ov;
  }
}

// ---------------- B: sim[b,i] += sum_{c in part} arr[b,c,i] * r[b,c] ----------------
// grid: stage0 [0,2240) stage1 [2240,2880) stage2 [2880,3200) stage3 [3200,3520)
// block = (s, b, part(16), chunk, arr(2)); 24 channels per block; 8-deep load batching
__global__ __launch_bounds__(256) void k_sim(Params P) {
  const int bid = blockIdx.x;
  int s, b, chunk, part, arr, HW;
  if (bid < 2240)      { s=0; int l=bid;      arr=l&1; l>>=1; part=l&15; l>>=4; chunk=l%7; b=l/7; HW=6400; }
  else if (bid < 2880) { s=1; int l=bid-2240; arr=l&1; l>>=1; part=l&15; l>>=4; chunk=l&1; b=l>>1; HW=1600; }
  else if (bid < 3200) { s=2; int l=bid-2880; arr=l&1; l>>=1; part=l&15; b=l>>4; chunk=0; HW=400; }
  else                 { s=3; int l=bid-3200; arr=l&1; l>>=1; part=l&15; b=l>>4; chunk=0; HW=100; }
  const int tid = threadIdx.x;
  const int c0 = part*24;
  const int hw4 = HW >> 2;

  __shared__ float rs[24];
  if (tid < 24) rs[tid] = P.r[(s*BT+b)*CC + c0 + tid];
  __syncthreads();

  const int i4 = chunk*256 + tid;
  if (i4 < hw4) {
    const float* src = arr ? po_of(P, s) : fm_of(P, s);
    const float4* ap = (const float4*)(src + ((size_t)b*CC + c0)*HW) + i4;
    float4 acc = {0.f, 0.f, 0.f, 0.f};
    for (int cb = 0; cb < 24; cb += 8) {
      float4 v[8];
      #pragma unroll
      for (int u = 0; u < 8; ++u) v[u] = ap[(size_t)(cb+u)*hw4];
      #pragma unroll
      for (int u = 0; u < 8; ++u) {
        const float rc = rs[cb+u];
        acc.x += v[u].x*rc; acc.y += v[u].y*rc; acc.z += v[u].z*rc; acc.w += v[u].w*rc;
      }
    }
    float* dst = P.simbuf + simoff(s) + b*HW + i4*4;
    atomicAdd(dst + 0, acc.x);
    atomicAdd(dst + 1, acc.y);
    atomicAdd(dst + 2, acc.z);
    atomicAdd(dst + 3, acc.w);
  }
}

// ---------------- C1: softmax in place over i, per (s,b) ----------------
__global__ __launch_bounds__(256) void k_softmax(Params P) {
  const int s = blockIdx.x / BT, b = blockIdx.x % BT;
  const int HW = hw_of(s);
  float* sim = P.simbuf + simoff(s) + b*HW;
  const int tid = threadIdx.x;
  const int wid = tid >> 6, lane = tid & 63;
  __shared__ float red[4], red2[4];

  float m = -1e30f;
  for (int i = tid; i < HW; i += 256) m = fmaxf(m, sim[i]);
  #pragma unroll
  for (int off = 32; off; off >>= 1) m = fmaxf(m, __shfl_down(m, off));
  if (lane == 0) red[wid] = m;
  __syncthreads();
  if (tid == 0) { float mm = red[0]; for (int w2 = 1; w2 < 4; ++w2) mm = fmaxf(mm, red[w2]); red[0] = mm; }
  __syncthreads();
  m = red[0];

  float sum = 0.f;
  for (int i = tid; i < HW; i += 256) { float e = expf(sim[i] - m); sim[i] = e; sum += e; }
  #pragma unroll
  for (int off = 32; off; off >>= 1) sum += __shfl_down(sum, off);
  if (lane == 0) red2[wid] = sum;
  __syncthreads();
  if (tid == 0) { float ss = red2[0]; for (int w2 = 1; w2 < 4; ++w2) ss += red2[w2]; red2[0] = ss; }
  __syncthreads();
  const float invS = 1.f / red2[0];

  for (int i = tid; i < HW; i += 256) sim[i] *= invS;
}

// ---------------- C2: xw[s,b,c] = sum_i w[b,i] * x[b,c,i]  (one wave per c, 4-deep batch) ----------------
__global__ __launch_bounds__(256) void k_xw(Params P) {
  const int bid = blockIdx.x;
  const int sb = bid / 96, ct = bid % 96;
  const int s = sb / BT, b = sb % BT;
  const int HW = hw_of(s);
  const int wid = threadIdx.x >> 6, lane = threadIdx.x & 63;
  const int c = ct*4 + wid;
  const float* xrow = fm_of(P, s) + ((size_t)(b*CC + c))*HW;
  const float* wrow = P.simbuf + simoff(s) + b*HW;
  float acc = 0.f;
  for (int i0 = lane*4; i0 < HW; i0 += 1024) {
    float4 x4[4], w4[4];
    #pragma unroll
    for (int u = 0; u < 4; ++u) {
      const int idx = i0 + u*256;
      if (idx < HW) { x4[u] = *(const float4*)(xrow + idx); w4[u] = *(const float4*)(wrow + idx); }
    }
    #pragma unroll
    for (int u = 0; u < 4; ++u) {
      const int idx = i0 + u*256;
      if (idx < HW) acc += x4[u].x*w4[u].x + x4[u].y*w4[u].y + x4[u].z*w4[u].z + x4[u].w*w4[u].w;
    }
  }
  #pragma unroll
  for (int off = 32; off; off >>= 1) acc += __shfl_down(acc, off);
  if (lane == 0) P.xw[(s*BT+b)*CC + c] = acc;
}

// ---------------- D: ctxo = Wv @ xw; aout = Wco @ ctxo + bco ----------------
__global__ __launch_bounds__(384) void k_post(Params P) {
  const int s = blockIdx.x / BT, b = blockIdx.x % BT;
  const int tid = threadIdx.x;
  __shared__ float xws[CC], ctxo[DH], pc[6][DH];
  xws[tid] = P.xw[(s*BT+b)*CC + tid];
  __syncthreads();
  {
    const int g = tid >> 6, oid = tid & 63;
    float a = 0.f;
    const float* wv = P.v_w + (size_t)(s*DH + oid)*CC + g*64;
    #pragma unroll 8
    for (int c = 0; c < 64; ++c) a += wv[c]*xws[g*64+c];
    pc[g][oid] = a;
  }
  __syncthreads();
  if (tid < DH) {
    float a = 0.f;
    #pragma unroll
    for (int g2 = 0; g2 < 6; ++g2) a += pc[g2][tid];
    ctxo[tid] = a;
  }
  __syncthreads();
  float ao = P.ctx_out_b[s*CC + tid];
  const float* wco = P.ctx_out_w + (size_t)(s*CC + tid)*DH;
  #pragma unroll 8
  for (int d = 0; d < DH; ++d) ao += wco[d]*ctxo[d];
  P.out[(size_t)AOUT_OFF + (s*BT+b)*CC + tid] = ao;
}

// ---------------- E: broadcast-fill vout ----------------
template<int F4PR, int VOFF, int OVOFF>
__device__ __forceinline__ void fill_one(const Params& P, int idx) {
  const int row = idx / F4PR;                 // magic-mul (compile-time divisor)
  const float val = P.outvec[OVOFF + row];
  const float4 v4 = {val, val, val, val};
  ((float4*)(P.out + VOFF))[idx] = v4;
}

__global__ __launch_bounds__(256) void k_fill(Params P) {
  const int gid = blockIdx.x * 256 + threadIdx.x;
  if (blockIdx.x < 24000)      fill_one<1600, VOFF0, 0>    (P, gid);
  else if (blockIdx.x < 30000) fill_one< 400, VOFF1, 3840> (P, gid - 24000*256);
  else if (blockIdx.x < 31500) fill_one< 100, VOFF2, 7680> (P, gid - 30000*256);
  else                         fill_one<  25, VOFF3, 11520>(P, gid - 31500*256);
}

extern "C" void kernel_launch(void* const* d_in, const int* in_sizes, int n_in,
                              void* d_out, int out_size, void* d_ws, size_t ws_size,
                              hipStream_t stream) {
  Params P;
  P.fmap0 = (const float*)d_in[0];  P.pos0 = (const float*)d_in[1];  P.audio0 = (const float*)d_in[2];
  P.fmap1 = (const float*)d_in[3];  P.pos1 = (const float*)d_in[4];  P.audio1 = (const float*)d_in[5];
  P.fmap2 = (const float*)d_in[6];  P.pos2 = (const float*)d_in[7];  P.audio2 = (const float*)d_in[8];
  P.fmap3 = (const float*)d_in[9];  P.pos3 = (const float*)d_in[10]; P.audio3 = (const float*)d_in[11];
  P.ctx_proj_w = (const float*)d_in[12]; P.ctx_proj_b = (const float*)d_in[13];
  P.pos_emb = (const float*)d_in[14];
  P.qk_w = (const float*)d_in[15];  P.ctx_qk_w = (const float*)d_in[16];
  P.v_w = (const float*)d_in[17];   P.ctx_v_w = (const float*)d_in[18];
  P.out_w = (const float*)d_in[19]; P.out_b = (const float*)d_in[20];
  P.ctx_out_w = (const float*)d_in[21]; P.ctx_out_b = (const float*)d_in[22];
  P.out = (float*)d_out;

  float* ws = (float*)d_ws;
  P.r      = ws;                 // 15360
  P.outvec = ws + 15360;         // 15360
  P.xw     = ws + 30720;         // 15360
  P.simbuf = ws + 46080;         // 85000

  hipMemsetAsync(P.simbuf, 0, 85000*sizeof(float), stream);
  k_pre    <<<NS*BT, 384, 0, stream>>>(P);
  k_sim    <<<3520,  256, 0, stream>>>(P);
  k_softmax<<<NS*BT, 256, 0, stream>>>(P);
  k_xw     <<<3840,  256, 0, stream>>>(P);   // fmap likely still LLC-resident after k_sim
  k_post   <<<NS*BT, 384, 0, stream>>>(P);
  k_fill   <<<31875, 256, 0, stream>>>(P);
}

// Round 5
// 435.624 us; speedup vs baseline: 1.0824x; 1.0125x over previous
//
#include <hip/hip_runtime.h>

#define BT 10
#define CC 384
#define DH 64
#define CTXC 128
#define NS 4
#define SCALE_F 0.125f

// vout offsets (floats) per stage, aout base
#define VOFF0 0
#define VOFF1 24576000
#define VOFF2 30720000
#define VOFF3 32256000
#define AOUT_OFF 32640000

#define SIM_TOT 85000   // floats per full sim image (all stages, all b)
#define NPART 16

struct Params {
  const float* fmap0; const float* fmap1; const float* fmap2; const float* fmap3;
  const float* pos0;  const float* pos1;  const float* pos2;  const float* pos3;
  const float* audio0;const float* audio1;const float* audio2;const float* audio3;
  const float* ctx_proj_w; const float* ctx_proj_b; const float* pos_emb;
  const float* qk_w; const float* ctx_qk_w; const float* v_w; const float* ctx_v_w;
  const float* out_w; const float* out_b; const float* ctx_out_w; const float* ctx_out_b;
  float* out;
  float* r;        // ws (4,10,384)
  float* outvec;   // ws (4,10,384)
  float* xw;       // ws (4,10,384)
  float* comb;     // ws 85000 (combined sim / softmax weights)
  float* part;     // ws 16 * 85000 (disjoint partials, no atomics)
};

__device__ __forceinline__ int hw_of(int s){ return s==0?6400: s==1?1600: s==2?400:100; }
__device__ __forceinline__ int simoff(int s){ return s==0?0: s==1?64000: s==2?80000:84000; }
__device__ __forceinline__ const float* fm_of(const Params& P, int s){ return s==0?P.fmap0: s==1?P.fmap1: s==2?P.fmap2:P.fmap3; }
__device__ __forceinline__ const float* po_of(const Params& P, int s){ return s==0?P.pos0: s==1?P.pos1: s==2?P.pos2:P.pos3; }
__device__ __forceinline__ const float* au_of(const Params& P, int s){ return s==0?P.audio0: s==1?P.audio1: s==2?P.audio2:P.audio3; }

// ---------------- A: per-(s,b) small GEMVs ----------------
__global__ __launch_bounds__(384) void k_pre(Params P) {
  const int s = blockIdx.x / BT, b = blockIdx.x % BT;
  const int tid = threadIdx.x;
  __shared__ float aud[CTXC], ctxv[CC], ctxpe[CC], cqk[DH], cvv[DH];
  __shared__ float pq[6][DH], pvv[6][DH];
  const float* audio = au_of(P, s);
  if (tid < CTXC) aud[tid] = audio[b*CTXC + tid];
  __syncthreads();
  {
    float acc = P.ctx_proj_b[s*CC + tid];
    const float4* wrow = (const float4*)(P.ctx_proj_w + (size_t)(s*CC + tid)*CTXC);
    #pragma unroll 8
    for (int k = 0; k < CTXC/4; ++k) {
      const float4 w = wrow[k];
      acc += w.x*aud[k*4] + w.y*aud[k*4+1] + w.z*aud[k*4+2] + w.w*aud[k*4+3];
    }
    ctxv[tid] = acc;
    ctxpe[tid] = acc + P.pos_emb[(s*5 + (b%5))*CC + tid];
  }
  __syncthreads();
  // cqk/cvv: 64 outputs x 384 dot, split over 6 groups of 64 threads
  {
    const int g = tid >> 6, oid = tid & 63;
    float q = 0.f, v = 0.f;
    const float4* wq = (const float4*)(P.ctx_qk_w + (size_t)(s*DH + oid)*CC + g*64);
    const float4* wv = (const float4*)(P.ctx_v_w  + (size_t)(s*DH + oid)*CC + g*64);
    #pragma unroll
    for (int u = 0; u < 16; ++u) {
      const float4 a = wq[u], c = wv[u];
      const int k0 = g*64 + u*4;
      q += a.x*ctxpe[k0] + a.y*ctxpe[k0+1] + a.z*ctxpe[k0+2] + a.w*ctxpe[k0+3];
      v += c.x*ctxv[k0]  + c.y*ctxv[k0+1]  + c.z*ctxv[k0+2]  + c.w*ctxv[k0+3];
    }
    pq[g][oid] = q; pvv[g][oid] = v;
  }
  __syncthreads();
  if (tid < DH) {
    float q = 0.f, v = 0.f;
    #pragma unroll
    for (int g2 = 0; g2 < 6; ++g2) { q += pq[g2][tid]; v += pvv[g2][tid]; }
    cqk[tid] = q; cvv[tid] = v;
  }
  __syncthreads();
  {
    float rr = 0.f, ov = P.out_b[s*CC + tid];
    const float* wqk = P.qk_w + (size_t)s*DH*CC + tid;        // [d][tid]: coalesced across tid
    const float4* wo = (const float4*)(P.out_w + (size_t)(s*CC + tid)*DH);
    #pragma unroll 8
    for (int d = 0; d < DH; ++d) rr += wqk[(size_t)d*CC]*cqk[d];
    #pragma unroll
    for (int u = 0; u < 16; ++u) {
      const float4 w = wo[u];
      ov += w.x*cvv[u*4] + w.y*cvv[u*4+1] + w.z*cvv[u*4+2] + w.w*cvv[u*4+3];
    }
    P.r[(s*BT+b)*CC + tid] = rr * SCALE_F;
    P.outvec[(s*BT+b)*CC + tid] = ov;
  }
}

// ---------------- B: part[p][b,i] = sum_{c in p} (x+pos)[b,c,i] * r[b,c]  (pure stores) ----------------
// grid 1760: s0 [0,1120) s1 [1120,1440) s2 [1440,1600) s3 [1600,1760)
// block = (s, b, part(16), chunk); 24 channels x 2 arrays per block, 8-deep load batching
__global__ __launch_bounds__(256) void k_sim(Params P) {
  const int bid = blockIdx.x;
  int s, b, chunk, part, HW;
  if (bid < 1120)      { s=0; int l=bid;      part=l&15; l>>=4; chunk=l%7; b=l/7; HW=6400; }
  else if (bid < 1440) { s=1; int l=bid-1120; part=l&15; l>>=4; chunk=l&1; b=l>>1; HW=1600; }
  else if (bid < 1600) { s=2; int l=bid-1440; part=l&15; b=l>>4; chunk=0; HW=400; }
  else                 { s=3; int l=bid-1600; part=l&15; b=l>>4; chunk=0; HW=100; }
  const int tid = threadIdx.x;
  const int c0 = part*24;
  const int hw4 = HW >> 2;

  __shared__ float rs[24];
  if (tid < 24) rs[tid] = P.r[(s*BT+b)*CC + c0 + tid];
  __syncthreads();

  const int i4 = chunk*256 + tid;
  if (i4 < hw4) {
    const float4* xp = (const float4*)(fm_of(P, s) + ((size_t)b*CC + c0)*HW) + i4;
    const float4* pp = (const float4*)(po_of(P, s) + ((size_t)b*CC + c0)*HW) + i4;
    float4 acc = {0.f, 0.f, 0.f, 0.f};
    #pragma unroll
    for (int cb = 0; cb < 24; cb += 8) {
      float4 v[8];
      #pragma unroll
      for (int u = 0; u < 8; ++u) v[u] = xp[(size_t)(cb+u)*hw4];
      #pragma unroll
      for (int u = 0; u < 8; ++u) {
        const float rc = rs[cb+u];
        acc.x += v[u].x*rc; acc.y += v[u].y*rc; acc.z += v[u].z*rc; acc.w += v[u].w*rc;
      }
    }
    #pragma unroll
    for (int cb = 0; cb < 24; cb += 8) {
      float4 v[8];
      #pragma unroll
      for (int u = 0; u < 8; ++u) v[u] = pp[(size_t)(cb+u)*hw4];
      #pragma unroll
      for (int u = 0; u < 8; ++u) {
        const float rc = rs[cb+u];
        acc.x += v[u].x*rc; acc.y += v[u].y*rc; acc.z += v[u].z*rc; acc.w += v[u].w*rc;
      }
    }
    *(float4*)(P.part + (size_t)part*SIM_TOT + simoff(s) + b*HW + i4*4) = acc;
  }
}

// ---------------- B2: comb[i] = sum_p part[p][i]  (wide, independent loads) ----------------
__global__ __launch_bounds__(256) void k_comb(Params P) {
  const int idx = blockIdx.x*256 + threadIdx.x;    // float4 index, 21250 total
  if (idx >= SIM_TOT/4) return;
  float4 acc = {0.f, 0.f, 0.f, 0.f};
  #pragma unroll
  for (int p = 0; p < NPART; ++p) {
    const float4 v = *(const float4*)(P.part + (size_t)p*SIM_TOT + idx*4);
    acc.x += v.x; acc.y += v.y; acc.z += v.z; acc.w += v.w;
  }
  *(float4*)(P.comb + idx*4) = acc;
}

// ---------------- C1: softmax in place over i, per (s,b) ----------------
__global__ __launch_bounds__(256) void k_softmax(Params P) {
  const int s = blockIdx.x / BT, b = blockIdx.x % BT;
  const int HW = hw_of(s);
  float* sim = P.comb + simoff(s) + b*HW;
  const int tid = threadIdx.x;
  const int wid = tid >> 6, lane = tid & 63;
  __shared__ float red[4], red2[4];

  float m = -1e30f;
  for (int i = tid; i < HW; i += 256) m = fmaxf(m, sim[i]);
  #pragma unroll
  for (int off = 32; off; off >>= 1) m = fmaxf(m, __shfl_down(m, off));
  if (lane == 0) red[wid] = m;
  __syncthreads();
  if (tid == 0) { float mm = red[0]; for (int w2 = 1; w2 < 4; ++w2) mm = fmaxf(mm, red[w2]); red[0] = mm; }
  __syncthreads();
  m = red[0];

  float sum = 0.f;
  for (int i = tid; i < HW; i += 256) { float e = expf(sim[i] - m); sim[i] = e; sum += e; }
  #pragma unroll
  for (int off = 32; off; off >>= 1) sum += __shfl_down(sum, off);
  if (lane == 0) red2[wid] = sum;
  __syncthreads();
  if (tid == 0) { float ss = red2[0]; for (int w2 = 1; w2 < 4; ++w2) ss += red2[w2]; red2[0] = ss; }
  __syncthreads();
  const float invS = 1.f / red2[0];

  for (int i = tid; i < HW; i += 256) sim[i] *= invS;
}

// ---------------- C2: xw[s,b,c] = sum_i w[b,i] * x[b,c,i]  (one wave per c, 4-deep batch) ----------------
__global__ __launch_bounds__(256) void k_xw(Params P) {
  const int bid = blockIdx.x;
  const int sb = bid / 96, ct = bid % 96;
  const int s = sb / BT, b = sb % BT;
  const int HW = hw_of(s);
  const int wid = threadIdx.x >> 6, lane = threadIdx.x & 63;
  const int c = ct*4 + wid;
  const float* xrow = fm_of(P, s) + ((size_t)(b*CC + c))*HW;
  const float* wrow = P.comb + simoff(s) + b*HW;
  float acc = 0.f;
  for (int i0 = lane*4; i0 < HW; i0 += 1024) {
    float4 x4[4], w4[4];
    #pragma unroll
    for (int u = 0; u < 4; ++u) {
      const int idx = i0 + u*256;
      if (idx < HW) { x4[u] = *(const float4*)(xrow + idx); w4[u] = *(const float4*)(wrow + idx); }
    }
    #pragma unroll
    for (int u = 0; u < 4; ++u) {
      const int idx = i0 + u*256;
      if (idx < HW) acc += x4[u].x*w4[u].x + x4[u].y*w4[u].y + x4[u].z*w4[u].z + x4[u].w*w4[u].w;
    }
  }
  #pragma unroll
  for (int off = 32; off; off >>= 1) acc += __shfl_down(acc, off);
  if (lane == 0) P.xw[(s*BT+b)*CC + c] = acc;
}

// ---------------- D: ctxo = Wv @ xw; aout = Wco @ ctxo + bco ----------------
__global__ __launch_bounds__(384) void k_post(Params P) {
  const int s = blockIdx.x / BT, b = blockIdx.x % BT;
  const int tid = threadIdx.x;
  __shared__ float xws[CC], ctxo[DH], pc[6][DH];
  xws[tid] = P.xw[(s*BT+b)*CC + tid];
  __syncthreads();
  {
    const int g = tid >> 6, oid = tid & 63;
    float a = 0.f;
    const float4* wv = (const float4*)(P.v_w + (size_t)(s*DH + oid)*CC + g*64);
    #pragma unroll
    for (int u = 0; u < 16; ++u) {
      const float4 w = wv[u];
      const int k0 = g*64 + u*4;
      a += w.x*xws[k0] + w.y*xws[k0+1] + w.z*xws[k0+2] + w.w*xws[k0+3];
    }
    pc[g][oid] = a;
  }
  __syncthreads();
  if (tid < DH) {
    float a = 0.f;
    #pragma unroll
    for (int g2 = 0; g2 < 6; ++g2) a += pc[g2][tid];
    ctxo[tid] = a;
  }
  __syncthreads();
  float ao = P.ctx_out_b[s*CC + tid];
  const float4* wco = (const float4*)(P.ctx_out_w + (size_t)(s*CC + tid)*DH);
  #pragma unroll
  for (int u = 0; u < 16; ++u) {
    const float4 w = wco[u];
    ao += w.x*ctxo[u*4] + w.y*ctxo[u*4+1] + w.z*ctxo[u*4+2] + w.w*ctxo[u*4+3];
  }
  P.out[(size_t)AOUT_OFF + (s*BT+b)*CC + tid] = ao;
}

// ---------------- E: broadcast-fill vout, 4 coalesced float4 stores/thread ----------------
template<int F4PR, int VOFF, int OVOFF, int MAXF4>
__device__ __forceinline__ void fill_one(const Params& P, int lb, int tid) {
  const int base = lb*1024;
  #pragma unroll
  for (int u = 0; u < 4; ++u) {
    const int idx = base + u*256 + tid;
    if (MAXF4 % 1024 != 0 && idx >= MAXF4) return;
    const int row = idx / F4PR;                 // magic-mul (compile-time divisor)
    const float val = P.outvec[OVOFF + row];
    const float4 v4 = {val, val, val, val};
    ((float4*)(P.out + VOFF))[idx] = v4;
  }
}

__global__ __launch_bounds__(256) void k_fill(Params P) {
  const int tid = threadIdx.x;
  if (blockIdx.x < 6000)      fill_one<1600, VOFF0, 0,     6144000>(P, blockIdx.x,        tid);
  else if (blockIdx.x < 7500) fill_one< 400, VOFF1, 3840,  1536000>(P, blockIdx.x - 6000, tid);
  else if (blockIdx.x < 7875) fill_one< 100, VOFF2, 7680,   384000>(P, blockIdx.x - 7500, tid);
  else                        fill_one<  25, VOFF3, 11520,   96000>(P, blockIdx.x - 7875, tid);
}

extern "C" void kernel_launch(void* const* d_in, const int* in_sizes, int n_in,
                              void* d_out, int out_size, void* d_ws, size_t ws_size,
                              hipStream_t stream) {
  Params P;
  P.fmap0 = (const float*)d_in[0];  P.pos0 = (const float*)d_in[1];  P.audio0 = (const float*)d_in[2];
  P.fmap1 = (const float*)d_in[3];  P.pos1 = (const float*)d_in[4];  P.audio1 = (const float*)d_in[5];
  P.fmap2 = (const float*)d_in[6];  P.pos2 = (const float*)d_in[7];  P.audio2 = (const float*)d_in[8];
  P.fmap3 = (const float*)d_in[9];  P.pos3 = (const float*)d_in[10]; P.audio3 = (const float*)d_in[11];
  P.ctx_proj_w = (const float*)d_in[12]; P.ctx_proj_b = (const float*)d_in[13];
  P.pos_emb = (const float*)d_in[14];
  P.qk_w = (const float*)d_in[15];  P.ctx_qk_w = (const float*)d_in[16];
  P.v_w = (const float*)d_in[17];   P.ctx_v_w = (const float*)d_in[18];
  P.out_w = (const float*)d_in[19]; P.out_b = (const float*)d_in[20];
  P.ctx_out_w = (const float*)d_in[21]; P.ctx_out_b = (const float*)d_in[22];
  P.out = (float*)d_out;

  float* ws = (float*)d_ws;
  P.r      = ws;                 // 15360
  P.outvec = ws + 15360;         // 15360
  P.xw     = ws + 30720;         // 15360
  P.comb   = ws + 46080;         // 85000
  P.part   = ws + 131080;        // 16 * 85000   (total ws ~5.97 MB)

  k_pre    <<<NS*BT, 384, 0, stream>>>(P);
  k_sim    <<<1760,  256, 0, stream>>>(P);
  k_comb   <<<84,    256, 0, stream>>>(P);
  k_softmax<<<NS*BT, 256, 0, stream>>>(P);
  k_xw     <<<3840,  256, 0, stream>>>(P);   // fmap likely still LLC-resident after k_sim
  k_post   <<<NS*BT, 384, 0, stream>>>(P);
  k_fill   <<<7969,  256, 0, stream>>>(P);
}